// Round 5
// baseline (804.645 us; speedup 1.0000x reference)
//
#include <hip/hip_runtime.h>
#include <hip/hip_bf16.h>

// B=256, S=512, D=128, R=2048, H=0.5
#define Bn 256
#define Sn 512
#define Dn 128
#define Rn 2048
#define TB 32
#define NBLK (Sn / TB)   // 16 time-blocks
#define LDX 136          // Xs LDS row stride (bf16)
#define LDP 2056         // PX LDS row stride (bf16): 4112 B -> +4 banks/row
#define LDI 132          // input-stage LDS row stride (fp32)
#define NT 1024          // threads per workgroup (16 waves)

using bf16_t = __hip_bfloat16;
typedef short bf16x8 __attribute__((ext_vector_type(8)));
typedef float f32x4 __attribute__((ext_vector_type(4)));
typedef float f32x2 __attribute__((ext_vector_type(2)));

__device__ __forceinline__ f32x2 clip2(f32x2 v) {
  v = __builtin_elementwise_max(v, (f32x2)(-5.f));
  v = __builtin_elementwise_min(v, (f32x2)(5.f));
  return v;
}

// fp32 -> bf16 bits, round-to-nearest-even (values finite/clamped here).
__device__ __forceinline__ unsigned bf16rne(float f) {
  const unsigned u = __float_as_uint(f);
  return (u + 0x7fffu + ((u >> 16) & 1u)) >> 16;
}
__device__ __forceinline__ unsigned pack_bf16(f32x2 v) {
  return (bf16rne(v.y) << 16) | (bf16rne(v.x) & 0xffffu);
}

// K0: weights fp32->bf16, zero loss accumulators. Grid covers exactly Rn*Dn.
__global__ __launch_bounds__(256) void k_prep(const float* __restrict__ Wp,
                                              const float* __restrict__ Wr,
                                              bf16_t* __restrict__ Wp_b,
                                              bf16_t* __restrict__ Wr_b,
                                              float* __restrict__ losses) {
  const int i = blockIdx.x * 256 + threadIdx.x;
  Wp_b[i] = __float2bfloat16(Wp[i]);
  Wr_b[i] = __float2bfloat16(Wr[i]);
  if (i == 0) { losses[0] = 0.f; losses[1] = 0.f; }
}

// Fused pipeline: one 1024-thread workgroup (16 waves, 4 waves/SIMD) per batch element.
__global__ __launch_bounds__(NT, 4) void k_fused(
    const float* __restrict__ inp,
    const float* __restrict__ om_i, const float* __restrict__ ga_i,
    const float* __restrict__ al_i,
    const bf16_t* __restrict__ Wp, const float* __restrict__ bp,
    const float* __restrict__ omr, const float* __restrict__ gar,
    const float* __restrict__ alr,
    const float* __restrict__ omo, const float* __restrict__ gao,
    const float* __restrict__ alo,
    const bf16_t* __restrict__ Wr, const float* __restrict__ br,
    float* __restrict__ preds, float* __restrict__ losses) {
  __shared__ bf16_t Xs[TB * LDX];    // 8.5 KB
  __shared__ bf16_t PX[TB * LDP];    // 128.5 KB (input stage / proj / x_out / D-partials)
  __shared__ float bpS[Rn];          // 8 KB
  __shared__ float brS[Dn];          // 0.5 KB
  __shared__ float smi[16], smo[16];

  const int tid = threadIdx.x;
  const int b = blockIdx.x;
  const int wv = tid >> 6, lane = tid & 63;
  const int lr = lane & 15, lq = lane >> 4;

  // bias preload (once)
  for (int i = tid; i < Rn; i += NT) bpS[i] = bp[i];
  if (tid < Dn) brS[tid] = br[tid];

  // input oscillator state (threads 0..127 own d = tid)
  float xi = 0.f, yi = 0.f, pc_in = 0.f;
  float w2i = 0.f, g2i = 0.f, ai = 0.f;
  if (tid < Dn) {
    w2i = om_i[tid] * om_i[tid];
    g2i = 2.f * fabsf(ga_i[tid]);
    ai = al_i[tid];
  }
  const float* inpb = inp + (size_t)b * Sn * Dn;

  // reservoir/output oscillator state: thread owns r = tid*2, tid*2+1 (one f32x2 pair)
  const int r0 = tid * 2;
  f32x2 xr = (f32x2)0.f, yr = (f32x2)0.f, xo = (f32x2)0.f, yo = (f32x2)0.f;
  f32x2 w2r, g2r, arv, w2o, g2o, aov;
  {
    f32x2 t;
    t = *(const f32x2*)(omr + r0); w2r = t * t;
    t = *(const f32x2*)(gar + r0); g2r = __builtin_elementwise_abs(t) * 2.f;
    arv = *(const f32x2*)(alr + r0);
    t = *(const f32x2*)(omo + r0); w2o = t * t;
    t = *(const f32x2*)(gao + r0); g2o = __builtin_elementwise_abs(t) * 2.f;
    aov = *(const f32x2*)(alo + r0);
  }
  f32x2 pc_out2 = (f32x2)0.f;

  float* Is = (float*)PX;                    // input staging overlay: [TB][LDI] fp32, 16.9 KB
  float* Pb = (float*)((char*)PX + 65536);   // D-phase partial overlay: 8*32*16 fp32 = 16 KB

  __syncthreads();  // bpS/brS ready

  for (int blk = 0; blk < NBLK; ++blk) {
    const int t0 = blk * TB;

    // ---- Phase A0: cooperative input-tile stage -> Is ----
    {
      const float* src = inpb + (size_t)t0 * Dn;
      const int row = tid >> 5, c4 = (tid & 31) * 4;  // 1024 threads cover 32x128/4 exactly
      *(f32x4*)&Is[row * LDI + c4] = *(const f32x4*)(src + (size_t)row * Dn + c4);
    }
    __syncthreads();

    // ---- Phase A: input oscillator, 32 steps (threads 0..127) ----
    if (tid < Dn) {
#pragma unroll
      for (int tt = 0; tt < TB; ++tt) {
        const float f = Is[tt * LDI + tid];
        if (t0 + tt > 0) { const float e = xi - f; pc_in += e * e; }
        const float accel = ai * f - g2i * yi - w2i * xi;
        const float xn = fminf(fmaxf(xi + 0.5f * yi, -5.f), 5.f);
        const float yn = fminf(fmaxf(yi + 0.5f * accel, -5.f), 5.f);
        Xs[tt * LDX + tid] = __float2bfloat16(xn);
        xi = xn; yi = yn;
      }
    }
    __syncthreads();  // Xs ready; Is dead -> PX writable

    // ---- Phase B: proj tile [32 x 2048] = Xs[32x128] @ Wp^T -> PX (bf16) ----
    {
      bf16x8 af[2][4];
#pragma unroll
      for (int i = 0; i < 2; ++i)
#pragma unroll
        for (int k = 0; k < 4; ++k)
          af[i][k] = *(const bf16x8*)&Xs[(i * 16 + lr) * LDX + k * 32 + lq * 8];

      const int n0w = wv * 128;  // wave's 128 r's, 8 j-tiles
      const bf16_t* wp_base = Wp + (size_t)(n0w + lr) * Dn + lq * 8;
      bf16x8 bf[2][4];
#pragma unroll
      for (int k = 0; k < 4; ++k) {
        bf[0][k] = *(const bf16x8*)(wp_base + (size_t)0 * 16 * Dn + k * 32);
        bf[1][k] = *(const bf16x8*)(wp_base + (size_t)1 * 16 * Dn + k * 32);
      }
      for (int j = 0; j < 8; ++j) {
        const int pb = j & 1;
        f32x4 acc[2] = {(f32x4)0.f, (f32x4)0.f};
#pragma unroll
        for (int k = 0; k < 4; ++k) {
          acc[0] = __builtin_amdgcn_mfma_f32_16x16x32_bf16(af[0][k], bf[pb][k], acc[0], 0, 0, 0);
          acc[1] = __builtin_amdgcn_mfma_f32_16x16x32_bf16(af[1][k], bf[pb][k], acc[1], 0, 0, 0);
        }
        if (j + 2 < 8) {
#pragma unroll
          for (int k = 0; k < 4; ++k)
            bf[pb][k] = *(const bf16x8*)(wp_base + (size_t)(j + 2) * 16 * Dn + k * 32);
        }
        const int col = n0w + j * 16 + lr;
        const float bv = bpS[col];
#pragma unroll
        for (int i = 0; i < 2; ++i)
#pragma unroll
          for (int r = 0; r < 4; ++r)
            PX[(i * 16 + lq * 4 + r) * LDP + col] = __float2bfloat16(acc[i][r] + bv);
      }
    }
    __syncthreads();

    // ---- Phase C: reservoir + output oscillators, in place in PX ----
    {
      unsigned pk = *(unsigned*)&PX[0 * LDP + r0];
      for (int tt = 0; tt < TB; ++tt) {
        unsigned pk_n = pk;
        if (tt + 1 < TB) pk_n = *(unsigned*)&PX[(tt + 1) * LDP + r0];
        f32x2 pv;
        pv.x = __uint_as_float(pk << 16);
        pv.y = __uint_as_float(pk & 0xffff0000u);
        f32x2 acr = arv * pv - g2r * yr - w2r * xr;
        f32x2 xrn = clip2(xr + yr * 0.5f);
        f32x2 yrn = clip2(yr + acr * 0.5f);
        f32x2 aco = aov * xrn - g2o * yo - w2o * xo;
        f32x2 xon = clip2(xo + yo * 0.5f);
        f32x2 yon = clip2(yo + aco * 0.5f);
        f32x2 e = xon - xrn;
        pc_out2 += e * e;
        xr = xrn; yr = yrn; xo = xon; yo = yon;
        *(unsigned*)&PX[tt * LDP + r0] = pack_bf16(xon);
        pk = pk_n;
      }
    }
    __syncthreads();

    // ---- Phase D: preds tile [32 x 128] = PX[32x2048] @ Wr^T + br ----
    // 16 waves: wave = (kh<<3)|ct. ct -> 16-col tile, kh -> K half (1024 each).
    {
      const int ct = wv & 7, kh = wv >> 3;
      const int d0 = ct * 16;
      const int kbase = kh * 1024;
      const bf16_t* wr_base = Wr + (size_t)(d0 + lr) * Rn + kbase + lq * 8;
      f32x4 acc[2][2] = {{(f32x4)0.f, (f32x4)0.f}, {(f32x4)0.f, (f32x4)0.f}};
      bf16x8 bcur = *(const bf16x8*)(wr_base);
#pragma unroll 2
      for (int k0 = 0; k0 < 1024; k0 += 32) {
        bf16x8 bnxt = bcur;
        if (k0 + 32 < 1024) bnxt = *(const bf16x8*)(wr_base + k0 + 32);
        const int par = (k0 >> 5) & 1;
        bf16x8 a0 = *(const bf16x8*)&PX[(0 + lr) * LDP + kbase + k0 + lq * 8];
        bf16x8 a1 = *(const bf16x8*)&PX[(16 + lr) * LDP + kbase + k0 + lq * 8];
        acc[0][par] = __builtin_amdgcn_mfma_f32_16x16x32_bf16(a0, bcur, acc[0][par], 0, 0, 0);
        acc[1][par] = __builtin_amdgcn_mfma_f32_16x16x32_bf16(a1, bcur, acc[1][par], 0, 0, 0);
        bcur = bnxt;
      }
      f32x4 accs[2];
      accs[0] = acc[0][0] + acc[0][1];
      accs[1] = acc[1][0] + acc[1][1];
      // combine K-halves through LDS overlay (PX is dead from here to next blk's B)
      if (kh == 1) {
#pragma unroll
        for (int i = 0; i < 2; ++i)
#pragma unroll
          for (int r = 0; r < 4; ++r)
            Pb[ct * 512 + (i * 16 + lq * 4 + r) * 16 + lr] = accs[i][r];
      }
      __syncthreads();
      if (kh == 0) {
        float* outb = preds + (size_t)b * Sn * Dn + (size_t)t0 * Dn;
        const int col = d0 + lr;
        const float bv = brS[col];
#pragma unroll
        for (int i = 0; i < 2; ++i)
#pragma unroll
          for (int r = 0; r < 4; ++r) {
            const int row = i * 16 + lq * 4 + r;
            outb[(size_t)row * Dn + col] = accs[i][r] + Pb[ct * 512 + row * 16 + lr] + bv;
          }
      }
    }
    __syncthreads();  // Pb reads done before next iteration's Is overlay write
  }

  // ---- loss reduction: one atomicAdd per block per loss ----
  float vi = pc_in;
  float vo = pc_out2.x + pc_out2.y;
#pragma unroll
  for (int o = 32; o > 0; o >>= 1) {
    vi += __shfl_down(vi, o, 64);
    vo += __shfl_down(vo, o, 64);
  }
  if (lane == 0) { smi[wv] = vi; smo[wv] = vo; }
  __syncthreads();
  if (tid == 0) {
    float si = 0.f, so = 0.f;
#pragma unroll
    for (int w = 0; w < 16; ++w) { si += smi[w]; so += smo[w]; }
    atomicAdd(losses + 0, si * (1.f / ((float)Bn * (float)Dn)));
    atomicAdd(losses + 1, so * (1.f / ((float)Bn * (float)Rn)));
  }
}

extern "C" void kernel_launch(void* const* d_in, const int* in_sizes, int n_in,
                              void* d_out, int out_size, void* d_ws, size_t ws_size,
                              hipStream_t stream) {
  const float* inputs    = (const float*)d_in[0];
  const float* omega_in  = (const float*)d_in[1];
  const float* gamma_in  = (const float*)d_in[2];
  const float* alpha_in  = (const float*)d_in[3];
  const float* W_proj    = (const float*)d_in[4];
  const float* b_proj    = (const float*)d_in[5];
  const float* omega_res = (const float*)d_in[6];
  const float* gamma_res = (const float*)d_in[7];
  const float* alpha_res = (const float*)d_in[8];
  const float* omega_out = (const float*)d_in[9];
  const float* gamma_out = (const float*)d_in[10];
  const float* alpha_out = (const float*)d_in[11];
  const float* W_read    = (const float*)d_in[12];
  const float* b_read    = (const float*)d_in[13];

  float* out = (float*)d_out;
  float* losses = out + (size_t)Bn * Sn * Dn;  // outputs concatenated: preds | pc_in | pc_out

  // ws: only 1 MB needed — bf16 copies of the two weight matrices.
  bf16_t* Wp_b = (bf16_t*)d_ws;
  bf16_t* Wr_b = Wp_b + (size_t)Rn * Dn;

  k_prep<<<1024, 256, 0, stream>>>(W_proj, W_read, Wp_b, Wr_b, losses);
  k_fused<<<Bn, NT, 0, stream>>>(inputs, omega_in, gamma_in, alpha_in,
                                 Wp_b, b_proj,
                                 omega_res, gamma_res, alpha_res,
                                 omega_out, gamma_out, alpha_out,
                                 Wr_b, b_read, out, losses);
}

// Round 6
// 679.709 us; speedup vs baseline: 1.1838x; 1.1838x over previous
//
#include <hip/hip_runtime.h>
#include <hip/hip_bf16.h>

// B=256, S=512, D=128, R=2048, H=0.5
#define Bn 256
#define Sn 512
#define Dn 128
#define Rn 2048
#define TB 32
#define NBLK (Sn / TB)   // 16 time-blocks
#define LDX 136          // Xs LDS row stride (bf16)
#define LDPs 1028        // PX LDS row stride (bf16), slice width 1024 + 4
#define LDI 132          // input-stage LDS row stride (fp32)
#define RG 1024          // r-slice per workgroup (G=2)

using bf16_t = __hip_bfloat16;
typedef short bf16x8 __attribute__((ext_vector_type(8)));
typedef float f32x4 __attribute__((ext_vector_type(4)));
typedef float f32x2 __attribute__((ext_vector_type(2)));

__device__ __forceinline__ f32x2 clip2(f32x2 v) {
  v = __builtin_elementwise_max(v, (f32x2)(-5.f));
  v = __builtin_elementwise_min(v, (f32x2)(5.f));
  return v;
}

// fp32 -> bf16 bits, round-to-nearest-even (values finite/clamped here).
__device__ __forceinline__ unsigned bf16rne(float f) {
  const unsigned u = __float_as_uint(f);
  return (u + 0x7fffu + ((u >> 16) & 1u)) >> 16;
}
__device__ __forceinline__ unsigned pack_bf16(f32x2 v) {
  return (bf16rne(v.y) << 16) | (bf16rne(v.x) & 0xffffu);
}

// K0: weights fp32->bf16, zero loss accumulators. Grid covers exactly Rn*Dn.
__global__ __launch_bounds__(256) void k_prep(const float* __restrict__ Wp,
                                              const float* __restrict__ Wr,
                                              bf16_t* __restrict__ Wp_b,
                                              bf16_t* __restrict__ Wr_b,
                                              float* __restrict__ losses) {
  const int i = blockIdx.x * 256 + threadIdx.x;
  Wp_b[i] = __float2bfloat16(Wp[i]);
  Wr_b[i] = __float2bfloat16(Wr[i]);
  if (i == 0) { losses[0] = 0.f; losses[1] = 0.f; }
}

// K1: init preds with broadcast bias (atomicAdd target). Grid covers Bn*Sn*Dn/4.
__global__ __launch_bounds__(256) void k_zero(float* __restrict__ preds,
                                              const float* __restrict__ br) {
  const int i = blockIdx.x * 256 + threadIdx.x;  // float4 index
  const f32x4 bv = *(const f32x4*)(br + (i & 31) * 4);
  *((f32x4*)preds + i) = bv;
}

// Fused pipeline: 512 workgroups (batch b = idx>>1, r-half g = idx&1), 512 thr (8 waves).
// LDS ~78.7 KB -> 2 WGs/CU, phases overlap ACROSS workgroups.
__global__ __launch_bounds__(512, 4) void k_fused(
    const float* __restrict__ inp,
    const float* __restrict__ om_i, const float* __restrict__ ga_i,
    const float* __restrict__ al_i,
    const bf16_t* __restrict__ Wp, const float* __restrict__ bp,
    const float* __restrict__ omr, const float* __restrict__ gar,
    const float* __restrict__ alr,
    const float* __restrict__ omo, const float* __restrict__ gao,
    const float* __restrict__ alo,
    const bf16_t* __restrict__ Wr,
    float* __restrict__ preds, float* __restrict__ losses) {
  __shared__ bf16_t Xs[TB * LDX];     // 8.5 KB
  __shared__ bf16_t PX[TB * LDPs];    // 64.25 KB (input stage / proj slice / x_out slice)
  __shared__ float bpS[RG];           // 4 KB (bias slice)
  __shared__ float smi[8], smo[8];

  const int tid = threadIdx.x;
  const int b = blockIdx.x >> 1, g = blockIdx.x & 1;
  const int rbase = g * RG;
  const int wv = tid >> 6, lane = tid & 63;
  const int lr = lane & 15, lq = lane >> 4;

  // bias slice preload (once)
  for (int i = tid; i < RG; i += 512) bpS[i] = bp[rbase + i];

  // input oscillator state (threads 0..127 own d = tid); duplicated across g.
  float xi = 0.f, yi = 0.f, pc_in = 0.f;
  float w2i = 0.f, g2i = 0.f, ai = 0.f;
  if (tid < Dn) {
    w2i = om_i[tid] * om_i[tid];
    g2i = 2.f * fabsf(ga_i[tid]);
    ai = al_i[tid];
  }
  const float* inpb = inp + (size_t)b * Sn * Dn;

  // reservoir/output oscillator state: thread owns local r = tid*2, tid*2+1.
  const int rl = tid * 2;
  f32x2 xr = (f32x2)0.f, yr = (f32x2)0.f, xo = (f32x2)0.f, yo = (f32x2)0.f;
  f32x2 w2r, g2r, arv, w2o, g2o, aov;
  {
    f32x2 t;
    t = *(const f32x2*)(omr + rbase + rl); w2r = t * t;
    t = *(const f32x2*)(gar + rbase + rl); g2r = __builtin_elementwise_abs(t) * 2.f;
    arv = *(const f32x2*)(alr + rbase + rl);
    t = *(const f32x2*)(omo + rbase + rl); w2o = t * t;
    t = *(const f32x2*)(gao + rbase + rl); g2o = __builtin_elementwise_abs(t) * 2.f;
    aov = *(const f32x2*)(alo + rbase + rl);
  }
  f32x2 pc_out2 = (f32x2)0.f;

  float* Is = (float*)PX;  // input staging overlay: [TB][LDI] fp32 = 16.9 KB

  __syncthreads();  // bpS ready

  for (int blk = 0; blk < NBLK; ++blk) {
    const int t0 = blk * TB;

    // ---- Phase A0: cooperative input-tile stage -> Is (non-temporal loads) ----
    {
      const float* src = inpb + (size_t)t0 * Dn;
      for (int i = tid; i < (TB * Dn) / 4; i += 512) {
        const int row = i >> 5, c4 = (i & 31) * 4;
        f32x4 v = __builtin_nontemporal_load((const f32x4*)(src + (size_t)row * Dn + c4));
        *(f32x4*)&Is[row * LDI + c4] = v;
      }
    }
    __syncthreads();

    // ---- Phase A: input oscillator, 32 steps (threads 0..127) ----
    if (tid < Dn) {
#pragma unroll
      for (int tt = 0; tt < TB; ++tt) {
        const float f = Is[tt * LDI + tid];
        if (t0 + tt > 0) { const float e = xi - f; pc_in += e * e; }
        const float accel = ai * f - g2i * yi - w2i * xi;
        const float xn = fminf(fmaxf(xi + 0.5f * yi, -5.f), 5.f);
        const float yn = fminf(fmaxf(yi + 0.5f * accel, -5.f), 5.f);
        Xs[tt * LDX + tid] = __float2bfloat16(xn);
        xi = xn; yi = yn;
      }
    }
    __syncthreads();  // Xs ready; Is dead -> PX writable

    // ---- Phase B: proj slice [32 x 1024] = Xs[32x128] @ Wp_slice^T -> PX (bf16) ----
    {
      bf16x8 af[2][4];
#pragma unroll
      for (int i = 0; i < 2; ++i)
#pragma unroll
        for (int k = 0; k < 4; ++k)
          af[i][k] = *(const bf16x8*)&Xs[(i * 16 + lr) * LDX + k * 32 + lq * 8];

      const int lb = wv * 128;  // local col base: wave's 128 r's, 8 j-tiles
      const bf16_t* wp_base = Wp + (size_t)(rbase + lb + lr) * Dn + lq * 8;
      bf16x8 bf[2][4];
#pragma unroll
      for (int k = 0; k < 4; ++k) {
        bf[0][k] = *(const bf16x8*)(wp_base + (size_t)0 * 16 * Dn + k * 32);
        bf[1][k] = *(const bf16x8*)(wp_base + (size_t)1 * 16 * Dn + k * 32);
      }
      for (int j = 0; j < 8; ++j) {
        const int pb = j & 1;
        f32x4 acc[2] = {(f32x4)0.f, (f32x4)0.f};
#pragma unroll
        for (int k = 0; k < 4; ++k) {
          acc[0] = __builtin_amdgcn_mfma_f32_16x16x32_bf16(af[0][k], bf[pb][k], acc[0], 0, 0, 0);
          acc[1] = __builtin_amdgcn_mfma_f32_16x16x32_bf16(af[1][k], bf[pb][k], acc[1], 0, 0, 0);
        }
        if (j + 2 < 8) {
#pragma unroll
          for (int k = 0; k < 4; ++k)
            bf[pb][k] = *(const bf16x8*)(wp_base + (size_t)(j + 2) * 16 * Dn + k * 32);
        }
        const int cl = lb + j * 16 + lr;
        const float bv = bpS[cl];
#pragma unroll
        for (int i = 0; i < 2; ++i)
#pragma unroll
          for (int r = 0; r < 4; ++r)
            PX[(i * 16 + lq * 4 + r) * LDPs + cl] = __float2bfloat16(acc[i][r] + bv);
      }
    }
    __syncthreads();

    // ---- Phase C: reservoir + output oscillators, in place in PX ----
    {
      unsigned pk = *(unsigned*)&PX[0 * LDPs + rl];
      for (int tt = 0; tt < TB; ++tt) {
        unsigned pk_n = pk;
        if (tt + 1 < TB) pk_n = *(unsigned*)&PX[(tt + 1) * LDPs + rl];
        f32x2 pv;
        pv.x = __uint_as_float(pk << 16);
        pv.y = __uint_as_float(pk & 0xffff0000u);
        f32x2 acr = arv * pv - g2r * yr - w2r * xr;
        f32x2 xrn = clip2(xr + yr * 0.5f);
        f32x2 yrn = clip2(yr + acr * 0.5f);
        f32x2 aco = aov * xrn - g2o * yo - w2o * xo;
        f32x2 xon = clip2(xo + yo * 0.5f);
        f32x2 yon = clip2(yo + aco * 0.5f);
        f32x2 e = xon - xrn;
        pc_out2 += e * e;
        xr = xrn; yr = yrn; xo = xon; yo = yon;
        *(unsigned*)&PX[tt * LDPs + rl] = pack_bf16(xon);
        pk = pk_n;
      }
    }
    __syncthreads();

    // ---- Phase D: partial preds [32 x 128] += PX[32x1024] @ Wr[:, slice]^T ----
    // 8 waves x 16 cols, full K-slice per wave; atomicAdd combine across g.
    {
      const int d0 = wv * 16;
      const bf16_t* wr_base = Wr + (size_t)(d0 + lr) * Rn + rbase + lq * 8;
      f32x4 acc[2][2] = {{(f32x4)0.f, (f32x4)0.f}, {(f32x4)0.f, (f32x4)0.f}};
      bf16x8 bcur = *(const bf16x8*)(wr_base);
#pragma unroll 2
      for (int k0 = 0; k0 < RG; k0 += 32) {
        bf16x8 bnxt = bcur;
        if (k0 + 32 < RG) bnxt = *(const bf16x8*)(wr_base + k0 + 32);
        const int par = (k0 >> 5) & 1;
        bf16x8 a0 = *(const bf16x8*)&PX[(0 + lr) * LDPs + k0 + lq * 8];
        bf16x8 a1 = *(const bf16x8*)&PX[(16 + lr) * LDPs + k0 + lq * 8];
        acc[0][par] = __builtin_amdgcn_mfma_f32_16x16x32_bf16(a0, bcur, acc[0][par], 0, 0, 0);
        acc[1][par] = __builtin_amdgcn_mfma_f32_16x16x32_bf16(a1, bcur, acc[1][par], 0, 0, 0);
        bcur = bnxt;
      }
      float* outb = preds + (size_t)b * Sn * Dn + (size_t)t0 * Dn;
      const int col = d0 + lr;
#pragma unroll
      for (int i = 0; i < 2; ++i) {
        f32x4 a = acc[i][0] + acc[i][1];
#pragma unroll
        for (int r = 0; r < 4; ++r) {
          const int row = i * 16 + lq * 4 + r;
          atomicAdd(outb + (size_t)row * Dn + col, a[r]);
        }
      }
    }
    __syncthreads();  // PX reads done before next iteration's Is overlay write
  }

  // ---- loss reduction: one atomicAdd per block per loss ----
  float vi = pc_in;
  float vo = pc_out2.x + pc_out2.y;
#pragma unroll
  for (int o = 32; o > 0; o >>= 1) {
    vi += __shfl_down(vi, o, 64);
    vo += __shfl_down(vo, o, 64);
  }
  if (lane == 0) { smi[wv] = vi; smo[wv] = vo; }
  __syncthreads();
  if (tid == 0) {
    float si = 0.f, so = 0.f;
#pragma unroll
    for (int w = 0; w < 8; ++w) { si += smi[w]; so += smo[w]; }
    if (g == 0) atomicAdd(losses + 0, si * (1.f / ((float)Bn * (float)Dn)));
    atomicAdd(losses + 1, so * (1.f / ((float)Bn * (float)Rn)));
  }
}

extern "C" void kernel_launch(void* const* d_in, const int* in_sizes, int n_in,
                              void* d_out, int out_size, void* d_ws, size_t ws_size,
                              hipStream_t stream) {
  const float* inputs    = (const float*)d_in[0];
  const float* omega_in  = (const float*)d_in[1];
  const float* gamma_in  = (const float*)d_in[2];
  const float* alpha_in  = (const float*)d_in[3];
  const float* W_proj    = (const float*)d_in[4];
  const float* b_proj    = (const float*)d_in[5];
  const float* omega_res = (const float*)d_in[6];
  const float* gamma_res = (const float*)d_in[7];
  const float* alpha_res = (const float*)d_in[8];
  const float* omega_out = (const float*)d_in[9];
  const float* gamma_out = (const float*)d_in[10];
  const float* alpha_out = (const float*)d_in[11];
  const float* W_read    = (const float*)d_in[12];
  const float* b_read    = (const float*)d_in[13];

  float* out = (float*)d_out;
  float* losses = out + (size_t)Bn * Sn * Dn;  // outputs concatenated: preds | pc_in | pc_out

  // ws: only 1 MB needed — bf16 copies of the two weight matrices.
  bf16_t* Wp_b = (bf16_t*)d_ws;
  bf16_t* Wr_b = Wp_b + (size_t)Rn * Dn;

  k_prep<<<1024, 256, 0, stream>>>(W_proj, W_read, Wp_b, Wr_b, losses);
  k_zero<<<(Bn * Sn * Dn / 4) / 256, 256, 0, stream>>>(out, b_read);
  k_fused<<<Bn * 2, 512, 0, stream>>>(inputs, omega_in, gamma_in, alpha_in,
                                      Wp_b, b_proj,
                                      omega_res, gamma_res, alpha_res,
                                      omega_out, gamma_out, alpha_out,
                                      Wr_b, out, losses);
}